// Round 5
// baseline (449.121 us; speedup 1.0000x reference)
//
#include <hip/hip_runtime.h>

#define N_NODES 100000
#define N_EDGES 1250000
#define F_RAW 48
#define F_LOC 16
#define F1 48
#define F_IN1 64   // F_RAW + F_LOC
#define F_IN2 64   // F1 + F_LOC
#define F_OUT 64

#define SCAN_SEG 1024
#define SCAN_NB ((N_NODES + SCAN_SEG - 1) / SCAN_SEG)  // 98
#define EHALF (N_EDGES / 2)

// ---------------------------------------------------------------------------
// Edge-index dtype detection (int64 vs int32 buffer).
// ---------------------------------------------------------------------------
__global__ void k_detect(const unsigned* edges_u32, int* flag) {
    __shared__ int any;
    if (threadIdx.x == 0) any = 0;
    __syncthreads();
    int nz = 0;
    for (int i = threadIdx.x; i < 2048; i += 256) {
        if (edges_u32[2 * i + 1] != 0u) nz = 1;
    }
    if (nz) atomicOr(&any, 1);
    __syncthreads();
    if (threadIdx.x == 0) *flag = any;
}

__device__ __forceinline__ void load_edge(const void* edges, int is32, int e,
                                          int& s, int& d) {
    if (is32) {
        const int* p = (const int*)edges;
        s = p[e];
        d = p[N_EDGES + e];
    } else {
        const long long* p = (const long long*)edges;
        s = (int)p[e];
        d = (int)p[N_EDGES + e];
    }
}

// deg[dst] += 1 (int histogram), 2 edges per thread
__global__ void k_deg(const void* edges, const int* flag, int* deg) {
    int i = blockIdx.x * blockDim.x + threadIdx.x;
    if (i >= EHALF) return;
    int is32 = *flag;
    int s0, d0, s1, d1;
    load_edge(edges, is32, i, s0, d0);
    load_edge(edges, is32, i + EHALF, s1, d1);
    (void)s0;
    (void)s1;
    atomicAdd(&deg[d0], 1);
    atomicAdd(&deg[d1], 1);
}

// --------------------------- hierarchical scan ------------------------------
__global__ __launch_bounds__(256) void k_scan_part(const int* __restrict__ deg,
                                                   int* __restrict__ bsum) {
    int b = blockIdx.x;
    int t = threadIdx.x;
    int i0 = b * SCAN_SEG + t * 4;
    int s = 0;
#pragma unroll
    for (int j = 0; j < 4; ++j) {
        int i = i0 + j;
        if (i < N_NODES) s += deg[i];
    }
#pragma unroll
    for (int m = 1; m < 64; m <<= 1) s += __shfl_xor(s, m);
    __shared__ int ws[4];
    if ((t & 63) == 0) ws[t >> 6] = s;
    __syncthreads();
    if (t == 0) bsum[b] = ws[0] + ws[1] + ws[2] + ws[3];
}

__global__ __launch_bounds__(128) void k_scan_top(int* __restrict__ bsum,
                                                  int* __restrict__ rowptr) {
    __shared__ int sh[128];
    int t = threadIdx.x;
    int v = (t < SCAN_NB) ? bsum[t] : 0;
    sh[t] = v;
    __syncthreads();
    for (int off = 1; off < 128; off <<= 1) {
        int u = (t >= off) ? sh[t - off] : 0;
        __syncthreads();
        sh[t] += u;
        __syncthreads();
    }
    if (t < SCAN_NB) bsum[t] = (t == 0) ? 0 : sh[t - 1];
    if (t == 127) rowptr[N_NODES] = sh[127];
}

__global__ __launch_bounds__(256) void k_scan_down(
    const int* __restrict__ deg, const int* __restrict__ bsum,
    int* __restrict__ rowptr, int* __restrict__ cnt,
    float* __restrict__ dinv) {
    int b = blockIdx.x;
    int t = threadIdx.x;
    int lane = t & 63;
    int wave = t >> 6;
    int i0 = b * SCAN_SEG + t * 4;
    int v[4];
    int s = 0;
#pragma unroll
    for (int j = 0; j < 4; ++j) {
        int i = i0 + j;
        v[j] = (i < N_NODES) ? deg[i] : 0;
        s += v[j];
    }
    int x = s;
#pragma unroll
    for (int off = 1; off < 64; off <<= 1) {
        int u = __shfl_up(x, off);
        if (lane >= off) x += u;
    }
    __shared__ int ws[4];
    if (lane == 63) ws[wave] = x;
    __syncthreads();
    int woff = 0;
    for (int w = 0; w < wave; ++w) woff += ws[w];
    int run = bsum[b] + woff + (x - s);
#pragma unroll
    for (int j = 0; j < 4; ++j) {
        int i = i0 + j;
        if (i < N_NODES) {
            rowptr[i] = run;
            cnt[i] = run;
            dinv[i] = rsqrtf((float)v[j] + 1.0f);
            run += v[j];
        }
    }
}

// fill CSR entries (src, dinv[src]) grouped by dst; 2 edges per thread
__global__ void k_fill(const void* edges, const int* flag,
                       const float* __restrict__ dinv, int* __restrict__ cnt,
                       int2* __restrict__ csr) {
    int i = blockIdx.x * blockDim.x + threadIdx.x;
    if (i >= EHALF) return;
    int is32 = *flag;
    int s0, d0, s1, d1;
    load_edge(edges, is32, i, s0, d0);
    load_edge(edges, is32, i + EHALF, s1, d1);
    float v0 = dinv[s0];
    float v1 = dinv[s1];
    int p0 = atomicAdd(&cnt[d0], 1);
    int p1 = atomicAdd(&cnt[d1], 1);
    csr[p0] = make_int2(s0, __float_as_int(v0));
    csr[p1] = make_int2(s1, __float_as_int(v1));
}

// h1 = [feat, loc] @ W1   (one wave per node, W1 in LDS)
__global__ __launch_bounds__(256) void k_h1(const float* __restrict__ feat,
                                            const float* __restrict__ loc,
                                            const float* __restrict__ W1,
                                            float* __restrict__ h1) {
    __shared__ float sW[F_IN1 * F1 + 64];
    for (int i = threadIdx.x; i < F_IN1 * F1; i += 256) sW[i] = W1[i];
    __syncthreads();
    int wave = threadIdx.x >> 6;
    int lane = threadIdx.x & 63;
    int node = blockIdx.x * 4 + wave;
    if (node >= N_NODES) return;
    float xl = (lane < F_RAW) ? feat[node * F_RAW + lane]
                              : loc[node * F_LOC + (lane - F_RAW)];
    float acc = 0.f;
#pragma unroll
    for (int k = 0; k < F_IN1; ++k) {
        float xk = __shfl(xl, k);
        acc = fmaf(xk, sW[k * F1 + lane], acc);
    }
    if (lane < F1) h1[node * F1 + lane] = acc;
}

__device__ __forceinline__ float4 xor4(float4 v, int m) {
    v.x += __shfl_xor(v.x, m);
    v.y += __shfl_xor(v.y, m);
    v.z += __shfl_xor(v.z, m);
    v.w += __shfl_xor(v.w, m);
    return v;
}

__device__ __forceinline__ float4 f4fma(float4 a, float c, float4 acc) {
    acc.x = fmaf(a.x, c, acc.x);
    acc.y = fmaf(a.y, c, acc.y);
    acc.z = fmaf(a.z, c, acc.z);
    acc.w = fmaf(a.w, c, acc.w);
    return acc;
}

// fused: agg1 (unroll-2 float4 gather) + self + bias + relu + GEMM W2 -> h2
__global__ __launch_bounds__(256) void k_mid(
    const float* __restrict__ h1, const float* __restrict__ dinv,
    const int* __restrict__ rowptr, const int2* __restrict__ csr,
    const float* __restrict__ loc, const float* __restrict__ W2,
    const float* __restrict__ b1, float* __restrict__ h2) {
    __shared__ float sW[F_IN2 * F_OUT];  // 16 KB
    for (int i = threadIdx.x; i < F_IN2 * F_OUT; i += 256) sW[i] = W2[i];
    __syncthreads();
    int wave = threadIdx.x >> 6;
    int lane = threadIdx.x & 63;
    int grp = lane >> 4;
    int l4 = lane & 15;
    int node = blockIdx.x * 4 + wave;
    if (node >= N_NODES) return;
    int r0 = rowptr[node], r1 = rowptr[node + 1];
    const float4* h1v = reinterpret_cast<const float4*>(h1);
    // preload independent data to overlap with edge chains
    float di = dinv[node];
    float locv = (lane >= F1) ? loc[node * F_LOC + (lane - F1)] : 0.f;
    float4 hs = make_float4(0.f, 0.f, 0.f, 0.f);
    float4 b4 = hs;
    float4 acc0 = hs, acc1 = hs;
    if (l4 < 12) {
        hs = h1v[(size_t)node * 12 + l4];
        b4 = reinterpret_cast<const float4*>(b1)[l4];
        int e = r0 + grp;
        while (e + 4 < r1) {
            int2 a = csr[e];
            int2 b = csr[e + 4];
            float4 vA = h1v[(size_t)a.x * 12 + l4];
            float4 vB = h1v[(size_t)b.x * 12 + l4];
            acc0 = f4fma(vA, __int_as_float(a.y), acc0);
            acc1 = f4fma(vB, __int_as_float(b.y), acc1);
            e += 8;
        }
        if (e < r1) {
            int2 a = csr[e];
            float4 vA = h1v[(size_t)a.x * 12 + l4];
            acc0 = f4fma(vA, __int_as_float(a.y), acc0);
        }
        acc0.x += acc1.x;
        acc0.y += acc1.y;
        acc0.z += acc1.z;
        acc0.w += acc1.w;
    }
    acc0 = xor4(acc0, 16);
    acc0 = xor4(acc0, 32);
    float d2 = di * di;
    float4 x4;
    x4.x = fmaxf(fmaf(acc0.x, di, fmaf(hs.x, d2, b4.x)), 0.f);
    x4.y = fmaxf(fmaf(acc0.y, di, fmaf(hs.y, d2, b4.y)), 0.f);
    x4.z = fmaxf(fmaf(acc0.z, di, fmaf(hs.z, d2, b4.z)), 0.f);
    x4.w = fmaxf(fmaf(acc0.w, di, fmaf(hs.w, d2, b4.w)), 0.f);
    float accv = 0.f;
#pragma unroll
    for (int k = 0; k < F1; ++k) {
        float comp = (k & 3) == 0   ? x4.x
                     : (k & 3) == 1 ? x4.y
                     : (k & 3) == 2 ? x4.z
                                    : x4.w;
        float xk = __shfl(comp, k >> 2);
        accv = fmaf(xk, sW[k * F_OUT + lane], accv);
    }
#pragma unroll
    for (int k = F1; k < F_IN2; ++k) {
        float xk = __shfl(locv, k);
        accv = fmaf(xk, sW[k * F_OUT + lane], accv);
    }
    h2[node * F_OUT + lane] = accv;
}

// fused: agg2 (unroll-2 float4 gather) + self + bias -> out
__global__ __launch_bounds__(256) void k_out(
    const float* __restrict__ h2, const float* __restrict__ dinv,
    const int* __restrict__ rowptr, const int2* __restrict__ csr,
    const float* __restrict__ b2, float* __restrict__ out) {
    int wave = threadIdx.x >> 6;
    int lane = threadIdx.x & 63;
    int grp = lane >> 4;
    int l4 = lane & 15;
    int node = blockIdx.x * 4 + wave;
    if (node >= N_NODES) return;
    int r0 = rowptr[node], r1 = rowptr[node + 1];
    const float4* h2v = reinterpret_cast<const float4*>(h2);
    float di = dinv[node];
    float4 hs = h2v[(size_t)node * 16 + l4];
    float4 acc0 = make_float4(0.f, 0.f, 0.f, 0.f);
    float4 acc1 = acc0;
    int e = r0 + grp;
    while (e + 4 < r1) {
        int2 a = csr[e];
        int2 b = csr[e + 4];
        float4 vA = h2v[(size_t)a.x * 16 + l4];
        float4 vB = h2v[(size_t)b.x * 16 + l4];
        acc0 = f4fma(vA, __int_as_float(a.y), acc0);
        acc1 = f4fma(vB, __int_as_float(b.y), acc1);
        e += 8;
    }
    if (e < r1) {
        int2 a = csr[e];
        float4 vA = h2v[(size_t)a.x * 16 + l4];
        acc0 = f4fma(vA, __int_as_float(a.y), acc0);
    }
    acc0.x += acc1.x;
    acc0.y += acc1.y;
    acc0.z += acc1.z;
    acc0.w += acc1.w;
    acc0 = xor4(acc0, 16);
    acc0 = xor4(acc0, 32);
    if (lane < 16) {
        float d2 = di * di;
        float4 b4 = reinterpret_cast<const float4*>(b2)[l4];
        float4 o;
        o.x = fmaf(acc0.x, di, fmaf(hs.x, d2, b4.x));
        o.y = fmaf(acc0.y, di, fmaf(hs.y, d2, b4.y));
        o.z = fmaf(acc0.z, di, fmaf(hs.z, d2, b4.z));
        o.w = fmaf(acc0.w, di, fmaf(hs.w, d2, b4.w));
        reinterpret_cast<float4*>(out + (size_t)node * F_OUT)[l4] = o;
    }
}

extern "C" void kernel_launch(void* const* d_in, const int* in_sizes, int n_in,
                              void* d_out, int out_size, void* d_ws,
                              size_t ws_size, hipStream_t stream) {
    const void* edges = d_in[0];
    const float* feat = (const float*)d_in[1];
    const float* loc = (const float*)d_in[2];
    const float* W1 = (const float*)d_in[3];
    const float* b1 = (const float*)d_in[4];
    const float* W2 = (const float*)d_in[5];
    const float* b2 = (const float*)d_in[6];
    float* out = (float*)d_out;

    char* ws = (char*)d_ws;
    float* dinv = (float*)(ws + 0);         //   400,000
    int* deg = (int*)(ws + 400000);         //   400,000
    int* rowptr = (int*)(ws + 800000);      //   400,016 (incl pad)
    int* cnt = (int*)(ws + 1200016);        //   400,000
    int2* csr = (int2*)(ws + 1600016);      // 10,000,000
    float* h1 = (float*)(ws + 11600016);    // 19,200,000
    float* h2 = (float*)(ws + 30800016);    // 25,600,000
    int* flag = (int*)(ws + 56400016);      // 4
    int* bsum = (int*)(ws + 56400032);      // 392 (scan partials)

    k_detect<<<1, 256, 0, stream>>>((const unsigned*)edges, flag);
    hipMemsetAsync(deg, 0, (size_t)N_NODES * 4, stream);
    k_deg<<<(EHALF + 255) / 256, 256, 0, stream>>>(edges, flag, deg);
    k_scan_part<<<SCAN_NB, 256, 0, stream>>>(deg, bsum);
    k_scan_top<<<1, 128, 0, stream>>>(bsum, rowptr);
    k_scan_down<<<SCAN_NB, 256, 0, stream>>>(deg, bsum, rowptr, cnt, dinv);
    k_fill<<<(EHALF + 255) / 256, 256, 0, stream>>>(edges, flag, dinv, cnt,
                                                    csr);
    k_h1<<<(N_NODES + 3) / 4, 256, 0, stream>>>(feat, loc, W1, h1);
    k_mid<<<(N_NODES + 3) / 4, 256, 0, stream>>>(h1, dinv, rowptr, csr, loc,
                                                 W2, b1, h2);
    k_out<<<(N_NODES + 3) / 4, 256, 0, stream>>>(h2, dinv, rowptr, csr, b2,
                                                 out);
}

// Round 6
// 425.353 us; speedup vs baseline: 1.0559x; 1.0559x over previous
//
#include <hip/hip_runtime.h>
#include <hip/hip_fp16.h>

#define N_NODES 100000
#define N_EDGES 1250000
#define F_RAW 48
#define F_LOC 16
#define F1 48
#define F_IN1 64   // F_RAW + F_LOC
#define F_IN2 64   // F1 + F_LOC
#define F_OUT 64

#define SCAN_SEG 1024
#define SCAN_NB ((N_NODES + SCAN_SEG - 1) / SCAN_SEG)  // 98
#define EHALF (N_EDGES / 2)

// ---------------------------------------------------------------------------
// Edge-index dtype detection (int64 vs int32 buffer).
// ---------------------------------------------------------------------------
__global__ void k_detect(const unsigned* edges_u32, int* flag) {
    __shared__ int any;
    if (threadIdx.x == 0) any = 0;
    __syncthreads();
    int nz = 0;
    for (int i = threadIdx.x; i < 2048; i += 256) {
        if (edges_u32[2 * i + 1] != 0u) nz = 1;
    }
    if (nz) atomicOr(&any, 1);
    __syncthreads();
    if (threadIdx.x == 0) *flag = any;
}

__device__ __forceinline__ void load_edge(const void* edges, int is32, int e,
                                          int& s, int& d) {
    if (is32) {
        const int* p = (const int*)edges;
        s = p[e];
        d = p[N_EDGES + e];
    } else {
        const long long* p = (const long long*)edges;
        s = (int)p[e];
        d = (int)p[N_EDGES + e];
    }
}

// deg[dst] += 1 (int histogram), 2 edges per thread
__global__ void k_deg(const void* edges, const int* flag, int* deg) {
    int i = blockIdx.x * blockDim.x + threadIdx.x;
    if (i >= EHALF) return;
    int is32 = *flag;
    int s0, d0, s1, d1;
    load_edge(edges, is32, i, s0, d0);
    load_edge(edges, is32, i + EHALF, s1, d1);
    (void)s0;
    (void)s1;
    atomicAdd(&deg[d0], 1);
    atomicAdd(&deg[d1], 1);
}

// --------------------------- hierarchical scan ------------------------------
__global__ __launch_bounds__(256) void k_scan_part(const int* __restrict__ deg,
                                                   int* __restrict__ bsum) {
    int b = blockIdx.x;
    int t = threadIdx.x;
    int i0 = b * SCAN_SEG + t * 4;
    int s = 0;
#pragma unroll
    for (int j = 0; j < 4; ++j) {
        int i = i0 + j;
        if (i < N_NODES) s += deg[i];
    }
#pragma unroll
    for (int m = 1; m < 64; m <<= 1) s += __shfl_xor(s, m);
    __shared__ int ws[4];
    if ((t & 63) == 0) ws[t >> 6] = s;
    __syncthreads();
    if (t == 0) bsum[b] = ws[0] + ws[1] + ws[2] + ws[3];
}

__global__ __launch_bounds__(128) void k_scan_top(int* __restrict__ bsum,
                                                  int* __restrict__ rowptr) {
    __shared__ int sh[128];
    int t = threadIdx.x;
    int v = (t < SCAN_NB) ? bsum[t] : 0;
    sh[t] = v;
    __syncthreads();
    for (int off = 1; off < 128; off <<= 1) {
        int u = (t >= off) ? sh[t - off] : 0;
        __syncthreads();
        sh[t] += u;
        __syncthreads();
    }
    if (t < SCAN_NB) bsum[t] = (t == 0) ? 0 : sh[t - 1];
    if (t == 127) rowptr[N_NODES] = sh[127];
}

__global__ __launch_bounds__(256) void k_scan_down(
    const int* __restrict__ deg, const int* __restrict__ bsum,
    int* __restrict__ rowptr, int* __restrict__ cnt,
    float* __restrict__ dinv) {
    int b = blockIdx.x;
    int t = threadIdx.x;
    int lane = t & 63;
    int wave = t >> 6;
    int i0 = b * SCAN_SEG + t * 4;
    int v[4];
    int s = 0;
#pragma unroll
    for (int j = 0; j < 4; ++j) {
        int i = i0 + j;
        v[j] = (i < N_NODES) ? deg[i] : 0;
        s += v[j];
    }
    int x = s;
#pragma unroll
    for (int off = 1; off < 64; off <<= 1) {
        int u = __shfl_up(x, off);
        if (lane >= off) x += u;
    }
    __shared__ int ws[4];
    if (lane == 63) ws[wave] = x;
    __syncthreads();
    int woff = 0;
    for (int w = 0; w < wave; ++w) woff += ws[w];
    int run = bsum[b] + woff + (x - s);
#pragma unroll
    for (int j = 0; j < 4; ++j) {
        int i = i0 + j;
        if (i < N_NODES) {
            rowptr[i] = run;
            cnt[i] = run;
            dinv[i] = rsqrtf((float)v[j] + 1.0f);
            run += v[j];
        }
    }
}

// fill CSR entries (src, dinv[src]) grouped by dst; 2 edges per thread
__global__ void k_fill(const void* edges, const int* flag,
                       const float* __restrict__ dinv, int* __restrict__ cnt,
                       int2* __restrict__ csr) {
    int i = blockIdx.x * blockDim.x + threadIdx.x;
    if (i >= EHALF) return;
    int is32 = *flag;
    int s0, d0, s1, d1;
    load_edge(edges, is32, i, s0, d0);
    load_edge(edges, is32, i + EHALF, s1, d1);
    float v0 = dinv[s0];
    float v1 = dinv[s1];
    int p0 = atomicAdd(&cnt[d0], 1);
    int p1 = atomicAdd(&cnt[d1], 1);
    csr[p0] = make_int2(s0, __float_as_int(v0));
    csr[p1] = make_int2(s1, __float_as_int(v1));
}

// h1 = [feat, loc] @ W1 -> fp16 rows of 64 halves (48 used + 16 zero pad)
__global__ __launch_bounds__(256) void k_h1(const float* __restrict__ feat,
                                            const float* __restrict__ loc,
                                            const float* __restrict__ W1,
                                            __half* __restrict__ h1h) {
    __shared__ float sW[F_IN1 * F1 + 64];
    for (int i = threadIdx.x; i < F_IN1 * F1; i += 256) sW[i] = W1[i];
    __syncthreads();
    int wave = threadIdx.x >> 6;
    int lane = threadIdx.x & 63;
    int node = blockIdx.x * 4 + wave;
    if (node >= N_NODES) return;
    float xl = (lane < F_RAW) ? feat[node * F_RAW + lane]
                              : loc[node * F_LOC + (lane - F_RAW)];
    float acc = 0.f;
#pragma unroll
    for (int k = 0; k < F_IN1; ++k) {
        float xk = __shfl(xl, k);
        acc = fmaf(xk, sW[k * F1 + lane], acc);
    }
    float v = (lane < F1) ? acc : 0.f;  // zero pad lanes 48..63
    h1h[(size_t)node * 64 + lane] = __float2half(v);
}

// fma 8 halves (one int4) * c into a[8]
__device__ __forceinline__ void fma8(const int4& p, float c, float a[8]) {
    const __half2* h = reinterpret_cast<const __half2*>(&p);
#pragma unroll
    for (int j = 0; j < 4; ++j) {
        float2 t = __half22float2(h[j]);
        a[2 * j] = fmaf(t.x, c, a[2 * j]);
        a[2 * j + 1] = fmaf(t.y, c, a[2 * j + 1]);
    }
}

__device__ __forceinline__ void red8(float a[8]) {
#pragma unroll
    for (int j = 0; j < 8; ++j) {
        a[j] += __shfl_xor(a[j], 8);
        a[j] += __shfl_xor(a[j], 16);
        a[j] += __shfl_xor(a[j], 32);
    }
}

// fused: agg1 (8-group fp16 gather) + self + bias + relu + GEMM W2 -> h2 (fp16)
__global__ __launch_bounds__(256) void k_mid(
    const __half* __restrict__ h1h, const float* __restrict__ dinv,
    const int* __restrict__ rowptr, const int2* __restrict__ csr,
    const float* __restrict__ loc, const float* __restrict__ W2,
    const float* __restrict__ b1, __half* __restrict__ h2h) {
    __shared__ float sW[F_IN2 * F_OUT];  // 16 KB
    for (int i = threadIdx.x; i < F_IN2 * F_OUT; i += 256) sW[i] = W2[i];
    __syncthreads();
    int wave = threadIdx.x >> 6;
    int lane = threadIdx.x & 63;
    int grp = lane >> 3;  // 8 edge groups
    int l8 = lane & 7;    // int4 slot within 128B row
    int node = blockIdx.x * 4 + wave;
    if (node >= N_NODES) return;
    int r0 = rowptr[node], r1 = rowptr[node + 1];
    const int4* h1x = reinterpret_cast<const int4*>(h1h);
    float di = dinv[node];
    float locv = (lane >= F1) ? loc[node * F_LOC + (lane - F1)] : 0.f;
    int4 hs = h1x[(size_t)node * 8 + l8];  // self row (fp16)
    float a0[8], a1[8];
#pragma unroll
    for (int j = 0; j < 8; ++j) a0[j] = a1[j] = 0.f;
    int e = r0 + grp;
    while (e + 8 < r1) {
        int2 A = csr[e];
        int2 B = csr[e + 8];
        int4 vA = h1x[(size_t)A.x * 8 + l8];
        int4 vB = h1x[(size_t)B.x * 8 + l8];
        fma8(vA, __int_as_float(A.y), a0);
        fma8(vB, __int_as_float(B.y), a1);
        e += 16;
    }
    if (e < r1) {
        int2 A = csr[e];
        int4 vA = h1x[(size_t)A.x * 8 + l8];
        fma8(vA, __int_as_float(A.y), a0);
    }
#pragma unroll
    for (int j = 0; j < 8; ++j) a0[j] += a1[j];
    red8(a0);  // a0[j] = full agg of feature l8*8+j, replicated over groups
    float d2 = di * di;
    float x1[8];
    if (l8 < 6) {  // features 0..47 only
        const float4* b1v = reinterpret_cast<const float4*>(b1);
        float4 bA = b1v[l8 * 2];
        float4 bB = b1v[l8 * 2 + 1];
        float bb[8] = {bA.x, bA.y, bA.z, bA.w, bB.x, bB.y, bB.z, bB.w};
        const __half2* hh = reinterpret_cast<const __half2*>(&hs);
#pragma unroll
        for (int j = 0; j < 4; ++j) {
            float2 t = __half22float2(hh[j]);
            x1[2 * j] = fmaxf(fmaf(a0[2 * j], di, fmaf(t.x, d2, bb[2 * j])), 0.f);
            x1[2 * j + 1] =
                fmaxf(fmaf(a0[2 * j + 1], di, fmaf(t.y, d2, bb[2 * j + 1])), 0.f);
        }
    } else {
#pragma unroll
        for (int j = 0; j < 8; ++j) x1[j] = 0.f;
    }
    float accv = 0.f;
#pragma unroll
    for (int k = 0; k < F1; ++k) {
        float xk = __shfl(x1[k & 7], k >> 3);
        accv = fmaf(xk, sW[k * F_OUT + lane], accv);
    }
#pragma unroll
    for (int k = F1; k < F_IN2; ++k) {
        float xk = __shfl(locv, k);
        accv = fmaf(xk, sW[k * F_OUT + lane], accv);
    }
    h2h[(size_t)node * 64 + lane] = __float2half(accv);
}

// fused: agg2 (8-group fp16 gather) + self + bias -> out (fp32)
__global__ __launch_bounds__(256) void k_out(
    const __half* __restrict__ h2h, const float* __restrict__ dinv,
    const int* __restrict__ rowptr, const int2* __restrict__ csr,
    const float* __restrict__ b2, float* __restrict__ out) {
    int wave = threadIdx.x >> 6;
    int lane = threadIdx.x & 63;
    int grp = lane >> 3;
    int l8 = lane & 7;
    int node = blockIdx.x * 4 + wave;
    if (node >= N_NODES) return;
    int r0 = rowptr[node], r1 = rowptr[node + 1];
    const int4* h2x = reinterpret_cast<const int4*>(h2h);
    float di = dinv[node];
    int4 hs = h2x[(size_t)node * 8 + l8];
    float a0[8], a1[8];
#pragma unroll
    for (int j = 0; j < 8; ++j) a0[j] = a1[j] = 0.f;
    int e = r0 + grp;
    while (e + 8 < r1) {
        int2 A = csr[e];
        int2 B = csr[e + 8];
        int4 vA = h2x[(size_t)A.x * 8 + l8];
        int4 vB = h2x[(size_t)B.x * 8 + l8];
        fma8(vA, __int_as_float(A.y), a0);
        fma8(vB, __int_as_float(B.y), a1);
        e += 16;
    }
    if (e < r1) {
        int2 A = csr[e];
        int4 vA = h2x[(size_t)A.x * 8 + l8];
        fma8(vA, __int_as_float(A.y), a0);
    }
#pragma unroll
    for (int j = 0; j < 8; ++j) a0[j] += a1[j];
    red8(a0);
    if (lane < 8) {  // grp 0 writes; each lane owns features l8*8..l8*8+7
        float d2 = di * di;
        const float4* b2v = reinterpret_cast<const float4*>(b2);
        float4 bA = b2v[l8 * 2];
        float4 bB = b2v[l8 * 2 + 1];
        float bb[8] = {bA.x, bA.y, bA.z, bA.w, bB.x, bB.y, bB.z, bB.w};
        const __half2* hh = reinterpret_cast<const __half2*>(&hs);
        float o[8];
#pragma unroll
        for (int j = 0; j < 4; ++j) {
            float2 t = __half22float2(hh[j]);
            o[2 * j] = fmaf(a0[2 * j], di, fmaf(t.x, d2, bb[2 * j]));
            o[2 * j + 1] = fmaf(a0[2 * j + 1], di, fmaf(t.y, d2, bb[2 * j + 1]));
        }
        float4* ov = reinterpret_cast<float4*>(out + (size_t)node * F_OUT);
        ov[l8 * 2] = make_float4(o[0], o[1], o[2], o[3]);
        ov[l8 * 2 + 1] = make_float4(o[4], o[5], o[6], o[7]);
    }
}

extern "C" void kernel_launch(void* const* d_in, const int* in_sizes, int n_in,
                              void* d_out, int out_size, void* d_ws,
                              size_t ws_size, hipStream_t stream) {
    const void* edges = d_in[0];
    const float* feat = (const float*)d_in[1];
    const float* loc = (const float*)d_in[2];
    const float* W1 = (const float*)d_in[3];
    const float* b1 = (const float*)d_in[4];
    const float* W2 = (const float*)d_in[5];
    const float* b2 = (const float*)d_in[6];
    float* out = (float*)d_out;

    char* ws = (char*)d_ws;
    float* dinv = (float*)(ws + 0);          //   400,000
    int* deg = (int*)(ws + 400000);          //   400,000
    int* rowptr = (int*)(ws + 800000);       //   400,016
    int* cnt = (int*)(ws + 1200016);         //   400,000
    int2* csr = (int2*)(ws + 1600016);       // 10,000,000
    __half* h1h = (__half*)(ws + 11600128);  // 12,800,000 (128B-aligned rows)
    __half* h2h = (__half*)(ws + 24400128);  // 12,800,000
    int* flag = (int*)(ws + 37200128);       // 4
    int* bsum = (int*)(ws + 37200144);       // 392

    k_detect<<<1, 256, 0, stream>>>((const unsigned*)edges, flag);
    hipMemsetAsync(deg, 0, (size_t)N_NODES * 4, stream);
    k_deg<<<(EHALF + 255) / 256, 256, 0, stream>>>(edges, flag, deg);
    k_scan_part<<<SCAN_NB, 256, 0, stream>>>(deg, bsum);
    k_scan_top<<<1, 128, 0, stream>>>(bsum, rowptr);
    k_scan_down<<<SCAN_NB, 256, 0, stream>>>(deg, bsum, rowptr, cnt, dinv);
    k_fill<<<(EHALF + 255) / 256, 256, 0, stream>>>(edges, flag, dinv, cnt,
                                                    csr);
    k_h1<<<(N_NODES + 3) / 4, 256, 0, stream>>>(feat, loc, W1, h1h);
    k_mid<<<(N_NODES + 3) / 4, 256, 0, stream>>>(h1h, dinv, rowptr, csr, loc,
                                                 W2, b1, h2h);
    k_out<<<(N_NODES + 3) / 4, 256, 0, stream>>>(h2h, dinv, rowptr, csr, b2,
                                                 out);
}

// Round 7
// 265.471 us; speedup vs baseline: 1.6918x; 1.6023x over previous
//
#include <hip/hip_runtime.h>
#include <hip/hip_fp16.h>

#define N_NODES 100000
#define N_EDGES 1250000
#define F_RAW 48
#define F_LOC 16
#define F1 48
#define F_IN1 64   // F_RAW + F_LOC
#define F_IN2 64   // F1 + F_LOC
#define F_OUT 64

#define SCAN_SEG 1024
#define SCAN_NB ((N_NODES + SCAN_SEG - 1) / SCAN_SEG)  // 98
#define EHALF (N_EDGES / 2)

typedef _Float16 half8_t __attribute__((ext_vector_type(8)));
typedef float floatx4 __attribute__((ext_vector_type(4)));

// ---------------------------------------------------------------------------
// Edge-index dtype detection (int64 vs int32 buffer).
// ---------------------------------------------------------------------------
__global__ void k_detect(const unsigned* edges_u32, int* flag) {
    __shared__ int any;
    if (threadIdx.x == 0) any = 0;
    __syncthreads();
    int nz = 0;
    for (int i = threadIdx.x; i < 2048; i += 256) {
        if (edges_u32[2 * i + 1] != 0u) nz = 1;
    }
    if (nz) atomicOr(&any, 1);
    __syncthreads();
    if (threadIdx.x == 0) *flag = any;
}

__device__ __forceinline__ void load_edge(const void* edges, int is32, int e,
                                          int& s, int& d) {
    if (is32) {
        const int* p = (const int*)edges;
        s = p[e];
        d = p[N_EDGES + e];
    } else {
        const long long* p = (const long long*)edges;
        s = (int)p[e];
        d = (int)p[N_EDGES + e];
    }
}

// deg[dst] += 1 (int histogram), 2 edges per thread
__global__ void k_deg(const void* edges, const int* flag, int* deg) {
    int i = blockIdx.x * blockDim.x + threadIdx.x;
    if (i >= EHALF) return;
    int is32 = *flag;
    int s0, d0, s1, d1;
    load_edge(edges, is32, i, s0, d0);
    load_edge(edges, is32, i + EHALF, s1, d1);
    (void)s0;
    (void)s1;
    atomicAdd(&deg[d0], 1);
    atomicAdd(&deg[d1], 1);
}

// --------------------------- hierarchical scan ------------------------------
__global__ __launch_bounds__(256) void k_scan_part(const int* __restrict__ deg,
                                                   int* __restrict__ bsum) {
    int b = blockIdx.x;
    int t = threadIdx.x;
    int i0 = b * SCAN_SEG + t * 4;
    int s = 0;
#pragma unroll
    for (int j = 0; j < 4; ++j) {
        int i = i0 + j;
        if (i < N_NODES) s += deg[i];
    }
#pragma unroll
    for (int m = 1; m < 64; m <<= 1) s += __shfl_xor(s, m);
    __shared__ int ws[4];
    if ((t & 63) == 0) ws[t >> 6] = s;
    __syncthreads();
    if (t == 0) bsum[b] = ws[0] + ws[1] + ws[2] + ws[3];
}

__global__ __launch_bounds__(128) void k_scan_top(int* __restrict__ bsum,
                                                  int* __restrict__ rowptr) {
    __shared__ int sh[128];
    int t = threadIdx.x;
    int v = (t < SCAN_NB) ? bsum[t] : 0;
    sh[t] = v;
    __syncthreads();
    for (int off = 1; off < 128; off <<= 1) {
        int u = (t >= off) ? sh[t - off] : 0;
        __syncthreads();
        sh[t] += u;
        __syncthreads();
    }
    if (t < SCAN_NB) bsum[t] = (t == 0) ? 0 : sh[t - 1];
    if (t == 127) rowptr[N_NODES] = sh[127];
}

__global__ __launch_bounds__(256) void k_scan_down(
    const int* __restrict__ deg, const int* __restrict__ bsum,
    int* __restrict__ rowptr, int* __restrict__ cnt,
    float* __restrict__ dinv) {
    int b = blockIdx.x;
    int t = threadIdx.x;
    int lane = t & 63;
    int wave = t >> 6;
    int i0 = b * SCAN_SEG + t * 4;
    int v[4];
    int s = 0;
#pragma unroll
    for (int j = 0; j < 4; ++j) {
        int i = i0 + j;
        v[j] = (i < N_NODES) ? deg[i] : 0;
        s += v[j];
    }
    int x = s;
#pragma unroll
    for (int off = 1; off < 64; off <<= 1) {
        int u = __shfl_up(x, off);
        if (lane >= off) x += u;
    }
    __shared__ int ws[4];
    if (lane == 63) ws[wave] = x;
    __syncthreads();
    int woff = 0;
    for (int w = 0; w < wave; ++w) woff += ws[w];
    int run = bsum[b] + woff + (x - s);
#pragma unroll
    for (int j = 0; j < 4; ++j) {
        int i = i0 + j;
        if (i < N_NODES) {
            rowptr[i] = run;
            cnt[i] = run;
            dinv[i] = rsqrtf((float)v[j] + 1.0f);
            run += v[j];
        }
    }
}

// fill CSR entries (src, dinv[src]) grouped by dst; 2 edges per thread
__global__ void k_fill(const void* edges, const int* flag,
                       const float* __restrict__ dinv, int* __restrict__ cnt,
                       int2* __restrict__ csr) {
    int i = blockIdx.x * blockDim.x + threadIdx.x;
    if (i >= EHALF) return;
    int is32 = *flag;
    int s0, d0, s1, d1;
    load_edge(edges, is32, i, s0, d0);
    load_edge(edges, is32, i + EHALF, s1, d1);
    float v0 = dinv[s0];
    float v1 = dinv[s1];
    int p0 = atomicAdd(&cnt[d0], 1);
    int p1 = atomicAdd(&cnt[d1], 1);
    csr[p0] = make_int2(s0, __float_as_int(v0));
    csr[p1] = make_int2(s1, __float_as_int(v1));
}

// ---------------------------------------------------------------------------
// x0 = concat(feat, loc) as fp16 rows of 64; thread per int4 (8 halves)
// ---------------------------------------------------------------------------
__global__ __launch_bounds__(256) void k_x0(const float* __restrict__ feat,
                                            const float* __restrict__ loc,
                                            __half* __restrict__ x0) {
    int idx = blockIdx.x * 256 + threadIdx.x;
    if (idx >= N_NODES * 8) return;
    int node = idx >> 3;
    int s = idx & 7;
    const float* srcp = (s < 6) ? feat + (size_t)node * F_RAW + s * 8
                                : loc + (size_t)node * F_LOC + (s - 6) * 8;
    float4 f0 = reinterpret_cast<const float4*>(srcp)[0];
    float4 f1 = reinterpret_cast<const float4*>(srcp)[1];
    __half2 q[4];
    q[0] = __halves2half2(__float2half(f0.x), __float2half(f0.y));
    q[1] = __halves2half2(__float2half(f0.z), __float2half(f0.w));
    q[2] = __halves2half2(__float2half(f1.x), __float2half(f1.y));
    q[3] = __halves2half2(__float2half(f1.z), __float2half(f1.w));
    reinterpret_cast<int4*>(x0)[idx] = *reinterpret_cast<int4*>(q);
}

// ---------------------------------------------------------------------------
// pack W [64][M] fp32 into MFMA B-fragment order, fp16.
// Wpk[((ct*2+kt)*64 + lane)*8 + j] = W[kt*32 + (lane>>4)*8 + j][ct*16+(lane&15)]
// ---------------------------------------------------------------------------
__global__ void k_wprep(const float* __restrict__ W, __half* __restrict__ Wpk,
                        int M, int CT) {
    int lane = threadIdx.x;  // 64 threads
    for (int ct = 0; ct < CT; ++ct)
        for (int kt = 0; kt < 2; ++kt)
            for (int j = 0; j < 8; ++j) {
                int k = kt * 32 + (lane >> 4) * 8 + j;
                int c = ct * 16 + (lane & 15);
                Wpk[((ct * 2 + kt) * 64 + lane) * 8 + j] =
                    __float2half(W[k * M + c]);
            }
}

// ---------------------------------------------------------------------------
// Y[node][c] = sum_k X[node][k] * W[k][c] via mfma_f32_16x16x32_f16.
// 32 nodes per wave (2 row-tiles), CT 16-col tiles, K=64 (2 k-steps).
// ZPAD: zero-fill cols 48..63 (pad slots 6,7) of each row.
// ---------------------------------------------------------------------------
template <int CT, int ZPAD>
__global__ __launch_bounds__(256) void k_gemm(const __half* __restrict__ X,
                                              const __half* __restrict__ Wpk,
                                              __half* __restrict__ Y) {
    int wid = threadIdx.x >> 6;
    int lane = threadIdx.x & 63;
    int nb = (blockIdx.x * 4 + wid) * 32;
    if (nb >= N_NODES) return;
    half8_t b[CT][2];
#pragma unroll
    for (int ct = 0; ct < CT; ++ct)
#pragma unroll
        for (int kt = 0; kt < 2; ++kt)
            b[ct][kt] =
                *reinterpret_cast<const half8_t*>(Wpk + ((ct * 2 + kt) * 64 + lane) * 8);
    int r = lane & 15;
    int ks = (lane >> 4) * 8;
    half8_t a[2][2];
#pragma unroll
    for (int rt = 0; rt < 2; ++rt)
#pragma unroll
        for (int kt = 0; kt < 2; ++kt)
            a[rt][kt] = *reinterpret_cast<const half8_t*>(
                X + ((size_t)(nb + rt * 16 + r) * 64 + kt * 32 + ks));
    floatx4 acc[2][CT];
#pragma unroll
    for (int rt = 0; rt < 2; ++rt)
#pragma unroll
        for (int ct = 0; ct < CT; ++ct) {
            floatx4 z = {0.f, 0.f, 0.f, 0.f};
            z = __builtin_amdgcn_mfma_f32_16x16x32_f16(a[rt][0], b[ct][0], z, 0, 0, 0);
            z = __builtin_amdgcn_mfma_f32_16x16x32_f16(a[rt][1], b[ct][1], z, 0, 0, 0);
            acc[rt][ct] = z;
        }
    int row0 = (lane >> 4) * 4;
    int col = lane & 15;
#pragma unroll
    for (int rt = 0; rt < 2; ++rt)
#pragma unroll
        for (int ct = 0; ct < CT; ++ct)
#pragma unroll
            for (int j = 0; j < 4; ++j) {
                int node = nb + rt * 16 + row0 + j;
                Y[(size_t)node * 64 + ct * 16 + col] = __float2half(acc[rt][ct][j]);
            }
    if (ZPAD) {
        int node = nb + (lane & 31);
        int slot = 6 + (lane >> 5);
        *reinterpret_cast<int4*>(Y + (size_t)node * 64 + slot * 8) =
            make_int4(0, 0, 0, 0);
    }
}

// ---------------------------------------------------------------------------
// gather helpers (fp16 rows of 64 halves, 8 groups x 8 lanes x int4)
// ---------------------------------------------------------------------------
__device__ __forceinline__ void fma8(const int4& p, float c, float a[8]) {
    const __half2* h = reinterpret_cast<const __half2*>(&p);
#pragma unroll
    for (int j = 0; j < 4; ++j) {
        float2 t = __half22float2(h[j]);
        a[2 * j] = fmaf(t.x, c, a[2 * j]);
        a[2 * j + 1] = fmaf(t.y, c, a[2 * j + 1]);
    }
}

__device__ __forceinline__ void red8(float a[8]) {
#pragma unroll
    for (int j = 0; j < 8; ++j) {
        a[j] += __shfl_xor(a[j], 8);
        a[j] += __shfl_xor(a[j], 16);
        a[j] += __shfl_xor(a[j], 32);
    }
}

// agg1: x1 = [relu(agg(h1)*di + h1*d2 + b1) (48) | loc (16)] as fp16 rows
__global__ __launch_bounds__(256) void k_agg1(
    const __half* __restrict__ h1h, const float* __restrict__ dinv,
    const int* __restrict__ rowptr, const int2* __restrict__ csr,
    const float* __restrict__ loc, const float* __restrict__ b1,
    __half* __restrict__ x1h) {
    int wave = threadIdx.x >> 6;
    int lane = threadIdx.x & 63;
    int grp = lane >> 3;
    int l8 = lane & 7;
    int node = blockIdx.x * 4 + wave;
    if (node >= N_NODES) return;
    int r0 = rowptr[node], r1 = rowptr[node + 1];
    const int4* h1x = reinterpret_cast<const int4*>(h1h);
    float di = dinv[node];
    int4 hs = h1x[(size_t)node * 8 + l8];
    float a0[8], a1[8];
#pragma unroll
    for (int j = 0; j < 8; ++j) a0[j] = a1[j] = 0.f;
    int e = r0 + grp;
    while (e + 8 < r1) {
        int2 A = csr[e];
        int2 B = csr[e + 8];
        int4 vA = h1x[(size_t)A.x * 8 + l8];
        int4 vB = h1x[(size_t)B.x * 8 + l8];
        fma8(vA, __int_as_float(A.y), a0);
        fma8(vB, __int_as_float(B.y), a1);
        e += 16;
    }
    if (e < r1) {
        int2 A = csr[e];
        int4 vA = h1x[(size_t)A.x * 8 + l8];
        fma8(vA, __int_as_float(A.y), a0);
    }
#pragma unroll
    for (int j = 0; j < 8; ++j) a0[j] += a1[j];
    red8(a0);
    if (lane < 8) {
        __half2 q[4];
        if (l8 < 6) {
            float d2 = di * di;
            const float4* b1v = reinterpret_cast<const float4*>(b1);
            float4 bA = b1v[l8 * 2];
            float4 bB = b1v[l8 * 2 + 1];
            float bb[8] = {bA.x, bA.y, bA.z, bA.w, bB.x, bB.y, bB.z, bB.w};
            const __half2* hh = reinterpret_cast<const __half2*>(&hs);
            float o[8];
#pragma unroll
            for (int j = 0; j < 4; ++j) {
                float2 t = __half22float2(hh[j]);
                o[2 * j] = fmaxf(fmaf(a0[2 * j], di, fmaf(t.x, d2, bb[2 * j])), 0.f);
                o[2 * j + 1] =
                    fmaxf(fmaf(a0[2 * j + 1], di, fmaf(t.y, d2, bb[2 * j + 1])), 0.f);
            }
#pragma unroll
            for (int j = 0; j < 4; ++j)
                q[j] = __halves2half2(__float2half(o[2 * j]), __float2half(o[2 * j + 1]));
        } else {
            const float* lp = loc + (size_t)node * F_LOC + (l8 - 6) * 8;
            float4 f0 = reinterpret_cast<const float4*>(lp)[0];
            float4 f1 = reinterpret_cast<const float4*>(lp)[1];
            q[0] = __halves2half2(__float2half(f0.x), __float2half(f0.y));
            q[1] = __halves2half2(__float2half(f0.z), __float2half(f0.w));
            q[2] = __halves2half2(__float2half(f1.x), __float2half(f1.y));
            q[3] = __halves2half2(__float2half(f1.z), __float2half(f1.w));
        }
        reinterpret_cast<int4*>(x1h)[(size_t)node * 8 + l8] =
            *reinterpret_cast<int4*>(q);
    }
}

// fused: agg2 (8-group fp16 gather) + self + bias -> out (fp32)
__global__ __launch_bounds__(256) void k_out(
    const __half* __restrict__ h2h, const float* __restrict__ dinv,
    const int* __restrict__ rowptr, const int2* __restrict__ csr,
    const float* __restrict__ b2, float* __restrict__ out) {
    int wave = threadIdx.x >> 6;
    int lane = threadIdx.x & 63;
    int grp = lane >> 3;
    int l8 = lane & 7;
    int node = blockIdx.x * 4 + wave;
    if (node >= N_NODES) return;
    int r0 = rowptr[node], r1 = rowptr[node + 1];
    const int4* h2x = reinterpret_cast<const int4*>(h2h);
    float di = dinv[node];
    int4 hs = h2x[(size_t)node * 8 + l8];
    float a0[8], a1[8];
#pragma unroll
    for (int j = 0; j < 8; ++j) a0[j] = a1[j] = 0.f;
    int e = r0 + grp;
    while (e + 8 < r1) {
        int2 A = csr[e];
        int2 B = csr[e + 8];
        int4 vA = h2x[(size_t)A.x * 8 + l8];
        int4 vB = h2x[(size_t)B.x * 8 + l8];
        fma8(vA, __int_as_float(A.y), a0);
        fma8(vB, __int_as_float(B.y), a1);
        e += 16;
    }
    if (e < r1) {
        int2 A = csr[e];
        int4 vA = h2x[(size_t)A.x * 8 + l8];
        fma8(vA, __int_as_float(A.y), a0);
    }
#pragma unroll
    for (int j = 0; j < 8; ++j) a0[j] += a1[j];
    red8(a0);
    if (lane < 8) {
        float d2 = di * di;
        const float4* b2v = reinterpret_cast<const float4*>(b2);
        float4 bA = b2v[l8 * 2];
        float4 bB = b2v[l8 * 2 + 1];
        float bb[8] = {bA.x, bA.y, bA.z, bA.w, bB.x, bB.y, bB.z, bB.w};
        const __half2* hh = reinterpret_cast<const __half2*>(&hs);
        float o[8];
#pragma unroll
        for (int j = 0; j < 4; ++j) {
            float2 t = __half22float2(hh[j]);
            o[2 * j] = fmaf(a0[2 * j], di, fmaf(t.x, d2, bb[2 * j]));
            o[2 * j + 1] = fmaf(a0[2 * j + 1], di, fmaf(t.y, d2, bb[2 * j + 1]));
        }
        float4* ov = reinterpret_cast<float4*>(out + (size_t)node * F_OUT);
        ov[l8 * 2] = make_float4(o[0], o[1], o[2], o[3]);
        ov[l8 * 2 + 1] = make_float4(o[4], o[5], o[6], o[7]);
    }
}

extern "C" void kernel_launch(void* const* d_in, const int* in_sizes, int n_in,
                              void* d_out, int out_size, void* d_ws,
                              size_t ws_size, hipStream_t stream) {
    const void* edges = d_in[0];
    const float* feat = (const float*)d_in[1];
    const float* loc = (const float*)d_in[2];
    const float* W1 = (const float*)d_in[3];
    const float* b1 = (const float*)d_in[4];
    const float* W2 = (const float*)d_in[5];
    const float* b2 = (const float*)d_in[6];
    float* out = (float*)d_out;

    char* ws = (char*)d_ws;
    float* dinv = (float*)(ws + 0);           //   400,000
    int* deg = (int*)(ws + 400000);           //   400,000
    int* rowptr = (int*)(ws + 800000);        //   400,016
    int* cnt = (int*)(ws + 1200016);          //   400,000
    int2* csr = (int2*)(ws + 1600016);        // 10,000,000
    __half* x0h = (__half*)(ws + 11600128);   // 12,800,000
    __half* h1h = (__half*)(ws + 24400128);   // 12,800,000
    __half* x1h = (__half*)(ws + 37200128);   // 12,800,000
    __half* h2h = (__half*)(ws + 50000128);   // 12,800,000
    __half* wpk1 = (__half*)(ws + 62800128);  //      6,144
    __half* wpk2 = (__half*)(ws + 62806272);  //      8,192
    int* flag = (int*)(ws + 62814464);        //          4
    int* bsum = (int*)(ws + 62814480);        //        392

    k_detect<<<1, 256, 0, stream>>>((const unsigned*)edges, flag);
    hipMemsetAsync(deg, 0, (size_t)N_NODES * 4, stream);
    k_wprep<<<1, 64, 0, stream>>>(W1, wpk1, F1, 3);
    k_wprep<<<1, 64, 0, stream>>>(W2, wpk2, F_OUT, 4);
    k_x0<<<(N_NODES * 8 + 255) / 256, 256, 0, stream>>>(feat, loc, x0h);
    k_deg<<<(EHALF + 255) / 256, 256, 0, stream>>>(edges, flag, deg);
    k_scan_part<<<SCAN_NB, 256, 0, stream>>>(deg, bsum);
    k_scan_top<<<1, 128, 0, stream>>>(bsum, rowptr);
    k_scan_down<<<SCAN_NB, 256, 0, stream>>>(deg, bsum, rowptr, cnt, dinv);
    k_fill<<<(EHALF + 255) / 256, 256, 0, stream>>>(edges, flag, dinv, cnt,
                                                    csr);
    int gblocks = (N_NODES / 32 + 3) / 4;  // 782
    k_gemm<3, 1><<<gblocks, 256, 0, stream>>>(x0h, wpk1, h1h);
    k_agg1<<<(N_NODES + 3) / 4, 256, 0, stream>>>(h1h, dinv, rowptr, csr, loc,
                                                  b1, x1h);
    k_gemm<4, 0><<<gblocks, 256, 0, stream>>>(x1h, wpk2, h2h);
    k_out<<<(N_NODES + 3) / 4, 256, 0, stream>>>(h2h, dinv, rowptr, csr, b2,
                                                 out);
}